// Round 12
// baseline (44377.084 us; speedup 1.0000x reference)
//
#include <hip/hip_runtime.h>
#include <math.h>

#define SEQ 8192
#define IN_DIM 128
#define HID 512
#define OUT_DIM 128
#define NK 9      // 8 spline basis + 1 silu slot
#define KNOTS 12

// ws layout (floats). W9HU region reused for W9O by build2 (after seq).
#define WS_W9HU  0                           // 128*9*512 = 589,824 (xpart W); later W9O (512*9*128)
#define WS_WSEQP 589824                      // 256*64*72 packed bf16-pair weights (as u32)
#define WS_XPART (WS_WSEQP + 1179648)        // 8192*512
#define WS_HCOMM (WS_XPART + 4194304)        // 8192*512
#define WS_TOTAL (WS_HCOMM + 4194304)        // ~40.6 MB

#define SENTINEL 0x7FA0DEADu   // sNaN payload; never produced by arithmetic

#define NWG 32
#define TPB2 512

typedef unsigned uint32x4 __attribute__((ext_vector_type(4)));

__device__ __forceinline__ int brow(int ib) { return ib*3 + (ib >> 4); }  // R2-proven (stride-16 reads)

__device__ __forceinline__ unsigned bf16rne(float f) {
    unsigned b = __float_as_uint(f);
    return (b + 0x7fffu + ((b >> 16) & 1u)) >> 16;
}
__device__ __forceinline__ float blo(unsigned p) { return __uint_as_float(p << 16); }
__device__ __forceinline__ float bhi(unsigned p) { return __uint_as_float(p & 0xffff0000u); }

// L1+L2-bypassing 16B load (reaches IF$, the agent coherence point)
__device__ __forceinline__ uint32x4 ld4_if(const unsigned* p) {
    uint32x4 r;
    asm volatile("global_load_dwordx4 %0, %1, off sc0 sc1\n\ts_waitcnt vmcnt(0)"
                 : "=v"(r) : "v"(p) : "memory");
    return r;
}

__device__ __forceinline__ void load_knots(const float* gptr, float* g, float* invA) {
    #pragma unroll
    for (int j = 0; j < KNOTS; ++j) g[j] = gptr[j];
    #pragma unroll
    for (int d = 1; d <= 3; ++d) {
        #pragma unroll
        for (int j = 0; j < 11; ++j) {
            if (j + d <= 11) invA[(d-1)*11 + j] = 1.0f / (g[j+d] - g[j]);
        }
    }
}

// Exact Cox-de Boor (degree 3) + silu — parallel kernels (R2-proven)
__device__ __forceinline__ void basis9(float x, const float* g, const float* invA, float* out) {
    float B[11];
    #pragma unroll
    for (int j = 0; j < 11; ++j)
        B[j] = (x >= g[j] && x < g[j+1]) ? 1.0f : 0.0f;
    #pragma unroll
    for (int d = 1; d <= 3; ++d) {
        #pragma unroll
        for (int j = 0; j < 11; ++j) {
            if (j + d < 11) {
                float left  = (x - g[j]) * invA[(d-1)*11 + j];
                float right = (g[j+d+1] - x) * invA[(d-1)*11 + j + 1];
                B[j] = left * B[j] + right * B[j+1];
            }
        }
    }
    #pragma unroll
    for (int j = 0; j < 8; ++j) out[j] = B[j];
    out[8] = x / (1.0f + expf(-x));
}

// ---------------- build1: xpart weights + packed wave-private seq weights + sentinel fill ----------------
__global__ __launch_bounds__(256) void build1_kernel(
    const float* __restrict__ hu_coef, const float* __restrict__ hu_sb, const float* __restrict__ hu_ssp,
    float* __restrict__ ws)
{
    int idx = blockIdx.x * blockDim.x + threadIdx.x;
    int stride = gridDim.x * blockDim.x;
    // xpart slab: [i<128][k<9][o<512]
    const int N1 = 128 * 9 * 512;
    for (int p = idx; p < N1; p += stride) {
        int o = p & 511; int k = (p >> 9) % 9; int i = p / 4608;
        float v = (k < 8) ? hu_ssp[i*HID + o] * hu_coef[(i*HID + o)*8 + k] : hu_sb[i*HID + o];
        ws[WS_W9HU + p] = v;
    }
    // packed seq slab: [opair<256][lane<64][slot<72]
    // lane covers inputs {4L+ci}(ci<4) and {256+4L+(ci-4)}(ci>=4); opair covers outputs {2*opair, 2*opair+1}
    unsigned* WP = (unsigned*)(ws + WS_WSEQP);
    const int N2 = 256 * 64 * 72;
    for (int p = idx; p < N2; p += stride) {
        int slot = p % 72; int lane = (p / 72) & 63; int opair = p / (72 * 64);
        unsigned pr;
        if (slot < 64) {
            int ci = slot >> 3, o = (slot >> 2) & 1, kp = slot & 3;
            int gi = IN_DIM + ((ci < 4) ? (4*lane + ci) : (256 + 4*lane + ci - 4));
            int oo = opair*2 + o;
            float wlo = hu_ssp[gi*HID + oo] * hu_coef[(gi*HID + oo)*8 + 2*kp];
            float whi = hu_ssp[gi*HID + oo] * hu_coef[(gi*HID + oo)*8 + 2*kp + 1];
            pr = bf16rne(wlo) | (bf16rne(whi) << 16);
        } else {
            int ci = slot - 64;
            int gi = IN_DIM + ((ci < 4) ? (4*lane + ci) : (256 + 4*lane + ci - 4));
            pr = bf16rne(hu_sb[gi*HID + opair*2]) | (bf16rne(hu_sb[gi*HID + opair*2 + 1]) << 16);
        }
        WP[p] = pr;
    }
    // sentinel fill
    unsigned* hc = (unsigned*)(ws + WS_HCOMM);
    for (int p = idx; p < SEQ*HID; p += stride) hc[p] = SENTINEL;
}

// ---------------- build2: output-layer weights (overlays W9HU; runs after seq) ----------------
__global__ __launch_bounds__(256) void build2_kernel(
    const float* __restrict__ out_coef, const float* __restrict__ out_sb, const float* __restrict__ out_ssp,
    float* __restrict__ ws)
{
    int idx = blockIdx.x * blockDim.x + threadIdx.x;
    int stride = gridDim.x * blockDim.x;
    const int N = 512 * 9 * 128;   // [i<512][k<9][o<128]
    for (int p = idx; p < N; p += stride) {
        int o = p & 127; int k = (p >> 7) % 9; int i = p / 1152;
        float v = (k < 8) ? out_ssp[i*OUT_DIM + o] * out_coef[(i*OUT_DIM + o)*8 + k] : out_sb[i*OUT_DIM + o];
        ws[WS_W9HU + p] = v;
    }
}

// ---------------- phase 1: x-part contributions (R2-proven form) ----------------
#define R1 4
__global__ __launch_bounds__(256) void xpart_kernel(
    const float* __restrict__ X, const float* __restrict__ hu_grid, float* __restrict__ ws)
{
    const int tid = threadIdx.x;
    const int t0 = blockIdx.x * R1;
    const float* W9 = ws + WS_W9HU;
    float* xpart = ws + WS_XPART;
    float g[KNOTS], invA[33];
    load_knots(hu_grid, g, invA);

    __shared__ float4 bas4[R1*IN_DIM*3 + (R1*IN_DIM)/16];
    #pragma unroll
    for (int rep = 0; rep < 2; ++rep) {
        int idx = tid + rep*256;
        int r = idx >> 7, i = idx & 127;
        float bv[9];
        basis9(X[(t0 + r)*IN_DIM + i], g, invA, bv);
        int rb = brow(idx);
        bas4[rb]   = make_float4(bv[0], bv[1], bv[2], bv[3]);
        bas4[rb+1] = make_float4(bv[4], bv[5], bv[6], bv[7]);
        bas4[rb+2] = make_float4(bv[8], 0.f, 0.f, 0.f);
    }
    __syncthreads();

    float acc[R1][2];
    #pragma unroll
    for (int r = 0; r < R1; ++r) { acc[r][0] = 0.f; acc[r][1] = 0.f; }

    for (int i = 0; i < IN_DIM; ++i) {
        float w1[9], w2[9];
        #pragma unroll
        for (int k = 0; k < 9; ++k) {
            w1[k] = W9[(i*NK+k)*HID + tid];
            w2[k] = W9[(i*NK+k)*HID + tid + 256];
        }
        #pragma unroll
        for (int r = 0; r < R1; ++r) {
            const float* rp = (const float*)&bas4[brow(r*IN_DIM + i)];
            float4 b0 = ((const float4*)rp)[0], b1 = ((const float4*)rp)[1];
            float b8 = rp[8];
            float s1 = w1[0]*b0.x + w1[1]*b0.y + w1[2]*b0.z + w1[3]*b0.w
                     + w1[4]*b1.x + w1[5]*b1.y + w1[6]*b1.z + w1[7]*b1.w + w1[8]*b8;
            float s2 = w2[0]*b0.x + w2[1]*b0.y + w2[2]*b0.z + w2[3]*b0.w
                     + w2[4]*b1.x + w2[5]*b1.y + w2[6]*b1.z + w2[7]*b1.w + w2[8]*b8;
            acc[r][0] += s1; acc[r][1] += s2;
        }
    }
    #pragma unroll
    for (int r = 0; r < R1; ++r) {
        xpart[(t0+r)*HID + tid]       = acc[r][0];
        xpart[(t0+r)*HID + tid + 256] = acc[r][1];
    }
}

// ---------------- phase 2: sequential recurrence (wave-autonomous: no LDS, no barriers) ----------------
__global__ __launch_bounds__(TPB2, 1) void seq_kernel(
    const float* __restrict__ h0, const float* __restrict__ hu_grid,
    const unsigned* __restrict__ WP,      // packed weights slab
    const float* __restrict__ xpart,
    unsigned* __restrict__ hcomm,         // u32 view of comm slab
    float* __restrict__ hs_out)
{
    const int tid   = threadIdx.x;
    const int lane  = tid & 63;
    const int wv    = tid >> 6;                   // wave 0..7
    const int opair = blockIdx.x * 8 + wv;        // 0..255
    const int o0    = opair * 2;
    const float g0 = hu_grid[0];
    const float inv_h = 1.0f / (hu_grid[1] - hu_grid[0]);

    // packed register-resident weights: 16 uint4 spline + 2 uint4 silu (static indices only)
    uint32x4 Wsp[16];
    uint32x4 Wsl0, Wsl1;
    {
        const uint32x4* Wb4 = (const uint32x4*)(WP + ((size_t)(opair*64 + lane))*72);
        #pragma unroll
        for (int r = 0; r < 16; ++r) Wsp[r] = Wb4[r];
        Wsl0 = Wb4[16]; Wsl1 = Wb4[17];
    }

    for (int t = 0; t < SEQ; ++t) {
        float xf0 = 0.f, xf1 = 0.f;
        if (lane == 0) {                           // poll-independent prefetch
            float2 xf = *(const float2*)&xpart[(size_t)t*HID + o0];
            xf0 = xf.x; xf1 = xf.y;
        }

        float hv[8];
        if (t == 0) {
            #pragma unroll
            for (int ci = 0; ci < 8; ++ci)
                hv[ci] = h0[(ci < 4) ? (4*lane + ci) : (256 + 4*lane + ci - 4)];
        } else {
            const unsigned* base = hcomm + (size_t)(t-1)*HID;
            const unsigned* p0 = base + 4*lane;
            const unsigned* p1 = base + 256 + 4*lane;
            int fails = 0;
            for (;;) {
                uint32x4 a = ld4_if(p0);
                uint32x4 b = ld4_if(p1);
                bool ok = (a.x != SENTINEL) & (a.y != SENTINEL) & (a.z != SENTINEL) & (a.w != SENTINEL)
                        & (b.x != SENTINEL) & (b.y != SENTINEL) & (b.z != SENTINEL) & (b.w != SENTINEL);
                if (ok) {
                    hv[0]=__uint_as_float(a.x); hv[1]=__uint_as_float(a.y);
                    hv[2]=__uint_as_float(a.z); hv[3]=__uint_as_float(a.w);
                    hv[4]=__uint_as_float(b.x); hv[5]=__uint_as_float(b.y);
                    hv[6]=__uint_as_float(b.z); hv[7]=__uint_as_float(b.w);
                    break;
                }
                if (++fails > (1 << 22)) {         // bounded escape; never hit in practice
                    hv[0]=__uint_as_float(a.x); hv[1]=__uint_as_float(a.y);
                    hv[2]=__uint_as_float(a.z); hv[3]=__uint_as_float(a.w);
                    hv[4]=__uint_as_float(b.x); hv[5]=__uint_as_float(b.y);
                    hv[6]=__uint_as_float(b.z); hv[7]=__uint_as_float(b.w);
                    break;
                }
                if (fails > 8) __builtin_amdgcn_s_sleep(1);   // backoff caps fabric pressure
            }
        }

        float a0 = 0.f, a1 = 0.f, a0b = 0.f, a1b = 0.f;
        #pragma unroll
        for (int ci = 0; ci < 8; ++ci) {
            float x  = hv[ci];
            float tq = (x - g0) * inv_h;
            float cf = floorf(tq);
            float uu = tq - cf;
            int   c  = (int)cf;
            float um = 1.0f - uu, u2 = uu*uu, u3 = u2*uu;
            float P0 = um*um*um*(1.0f/6.0f);
            float P1 = 0.5f*u3 - u2 + (2.0f/3.0f);
            float P2 = -0.5f*u3 + 0.5f*u2 + 0.5f*uu + (1.0f/6.0f);
            float P3 = u3*(1.0f/6.0f);
            float b[8];
            #pragma unroll
            for (int k = 0; k < 8; ++k) {
                float v = 0.f;
                v = (c == k+3) ? P0 : v;
                v = (c == k+2) ? P1 : v;
                v = (c == k+1) ? P2 : v;
                v = (c == k  ) ? P3 : v;
                b[k] = v;
            }
            float si = x * __builtin_amdgcn_rcpf(1.0f + __expf(-x));
            uint32x4 w0 = Wsp[ci*2 + 0];
            uint32x4 w1 = Wsp[ci*2 + 1];
            float s0 = blo(w0.x)*b[0] + bhi(w0.x)*b[1] + blo(w0.y)*b[2] + bhi(w0.y)*b[3]
                     + blo(w0.z)*b[4] + bhi(w0.z)*b[5] + blo(w0.w)*b[6] + bhi(w0.w)*b[7];
            float s1 = blo(w1.x)*b[0] + bhi(w1.x)*b[1] + blo(w1.y)*b[2] + bhi(w1.y)*b[3]
                     + blo(w1.z)*b[4] + bhi(w1.z)*b[5] + blo(w1.w)*b[6] + bhi(w1.w)*b[7];
            unsigned sl;
            if      (ci == 0) sl = Wsl0.x; else if (ci == 1) sl = Wsl0.y;
            else if (ci == 2) sl = Wsl0.z; else if (ci == 3) sl = Wsl0.w;
            else if (ci == 4) sl = Wsl1.x; else if (ci == 5) sl = Wsl1.y;
            else if (ci == 6) sl = Wsl1.z; else              sl = Wsl1.w;
            s0 += blo(sl)*si;
            s1 += bhi(sl)*si;
            if (ci & 1) { a0b += s0; a1b += s1; } else { a0 += s0; a1 += s1; }
        }
        a0 += a0b; a1 += a1b;

        #pragma unroll
        for (int d = 1; d < 64; d <<= 1) {
            a0 += __shfl_xor(a0, d, 64);
            a1 += __shfl_xor(a1, d, 64);
        }
        if (lane == 0) {
            float s0f = a0 + xf0, s1f = a1 + xf1;
            __hip_atomic_store(&hcomm[(size_t)t*HID + o0],     __float_as_uint(s0f),
                               __ATOMIC_RELAXED, __HIP_MEMORY_SCOPE_AGENT);
            __hip_atomic_store(&hcomm[(size_t)t*HID + o0 + 1], __float_as_uint(s1f),
                               __ATOMIC_RELAXED, __HIP_MEMORY_SCOPE_AGENT);
            hs_out[(size_t)t*HID + o0]     = s0f;
            hs_out[(size_t)t*HID + o0 + 1] = s1f;
        }
    }
}

// ---------------- phase 3: output layer (R2-proven form) ----------------
#define R3 2
__global__ __launch_bounds__(256) void outlayer_kernel(
    const float* __restrict__ out_grid, float* __restrict__ ws, float* __restrict__ d_out)
{
    const int tid = threadIdx.x;
    const int t0 = blockIdx.x * R3;
    const float* W9o = ws + WS_W9HU;   // overlaid by build2
    const float* hs = d_out + (size_t)SEQ*OUT_DIM;
    float g[KNOTS], invA[33];
    load_knots(out_grid, g, invA);

    __shared__ float4 bas4[R3*HID*3 + (R3*HID)/16];
    #pragma unroll
    for (int rep = 0; rep < 4; ++rep) {
        int idx = tid + rep*256;
        int r = idx >> 9, i = idx & 511;
        float bv[9];
        basis9(hs[(size_t)(t0+r)*HID + i], g, invA, bv);
        int rb = brow(idx);
        bas4[rb]   = make_float4(bv[0], bv[1], bv[2], bv[3]);
        bas4[rb+1] = make_float4(bv[4], bv[5], bv[6], bv[7]);
        bas4[rb+2] = make_float4(bv[8], 0.f, 0.f, 0.f);
    }
    __syncthreads();

    const int oo = tid & 127;
    const int half = tid >> 7;
    float acc[R3] = {0.f, 0.f};
    for (int ii = 0; ii < 256; ++ii) {
        int i = half*256 + ii;
        float wv[9];
        #pragma unroll
        for (int k = 0; k < 9; ++k) wv[k] = W9o[(i*NK+k)*OUT_DIM + oo];
        #pragma unroll
        for (int r = 0; r < R3; ++r) {
            const float* rp = (const float*)&bas4[brow(r*HID + i)];
            float4 b0 = ((const float4*)rp)[0], b1 = ((const float4*)rp)[1];
            float b8 = rp[8];
            acc[r] += wv[0]*b0.x + wv[1]*b0.y + wv[2]*b0.z + wv[3]*b0.w
                    + wv[4]*b1.x + wv[5]*b1.y + wv[6]*b1.z + wv[7]*b1.w + wv[8]*b8;
        }
    }
    __shared__ float red[2][R3][128];
    red[half][0][oo] = acc[0];
    red[half][1][oo] = acc[1];
    __syncthreads();
    {
        int rr = tid >> 7, o2 = tid & 127;
        d_out[(size_t)(t0+rr)*OUT_DIM + o2] = red[0][rr][o2] + red[1][rr][o2];
    }
}

extern "C" void kernel_launch(void* const* d_in, const int* in_sizes, int n_in,
                              void* d_out, int out_size, void* d_ws, size_t ws_size,
                              hipStream_t stream) {
    (void)in_sizes; (void)n_in; (void)out_size; (void)ws_size;
    const float* X        = (const float*)d_in[0];
    const float* h0       = (const float*)d_in[1];
    const float* hu_grid  = (const float*)d_in[2];
    const float* hu_coef  = (const float*)d_in[3];
    const float* hu_sb    = (const float*)d_in[4];
    const float* hu_ssp   = (const float*)d_in[5];
    const float* out_grid = (const float*)d_in[6];
    const float* out_coef = (const float*)d_in[7];
    const float* out_sb   = (const float*)d_in[8];
    const float* out_ssp  = (const float*)d_in[9];
    float* out = (float*)d_out;
    float* ws  = (float*)d_ws;

    hipLaunchKernelGGL(build1_kernel, dim3(2048), dim3(256), 0, stream,
                       hu_coef, hu_sb, hu_ssp, ws);
    hipLaunchKernelGGL(xpart_kernel, dim3(SEQ/R1), dim3(256), 0, stream, X, hu_grid, ws);
    hipLaunchKernelGGL(seq_kernel, dim3(NWG), dim3(TPB2), 0, stream,
                       h0, hu_grid,
                       (const unsigned*)(ws + WS_WSEQP),
                       ws + WS_XPART,
                       (unsigned*)(ws + WS_HCOMM),
                       out + (size_t)SEQ*OUT_DIM);
    hipLaunchKernelGGL(build2_kernel, dim3(1024), dim3(256), 0, stream,
                       out_coef, out_sb, out_ssp, ws);
    hipLaunchKernelGGL(outlayer_kernel, dim3(SEQ/R3), dim3(256), 0, stream, out_grid, ws, out);
}

// Round 13
// 20436.868 us; speedup vs baseline: 2.1714x; 2.1714x over previous
//
#include <hip/hip_runtime.h>
#include <math.h>

#define SEQ 8192
#define IN_DIM 128
#define HID 512
#define OUT_DIM 128
#define NK 9      // 8 spline basis + 1 silu slot
#define KNOTS 12

// ws layout (floats). W9HU region reused for W9O by build2 (after seq).
#define WS_W9HU  0                           // 128*9*512 = 589,824 (xpart W); later W9O (512*9*128)
#define WS_WSEQP 589824                      // 32*512*72 packed bf16-pair weights (as u32)
#define WS_XPART (WS_WSEQP + 1179648)        // 8192*512
#define WS_HCOMM (WS_XPART + 4194304)        // 8192*512
#define WS_TOTAL (WS_HCOMM + 4194304)        // ~40.6 MB

#define SENTINEL 0x7FA0DEADu   // sNaN payload; never produced by arithmetic

#define NWG 32
#define TPB2 512

typedef unsigned uint32x4 __attribute__((ext_vector_type(4)));

__device__ __forceinline__ int brow(int ib) { return ib*3 + (ib >> 4); }  // R2-proven (stride-16 reads)

__device__ __forceinline__ unsigned bf16rne(float f) {
    unsigned b = __float_as_uint(f);
    return (b + 0x7fffu + ((b >> 16) & 1u)) >> 16;
}
__device__ __forceinline__ float blo(unsigned p) { return __uint_as_float(p << 16); }
__device__ __forceinline__ float bhi(unsigned p) { return __uint_as_float(p & 0xffff0000u); }

// L1+L2-bypassing 16B load (reaches IF$, the agent coherence point) — R12-proven correct
__device__ __forceinline__ uint32x4 ld4_if(const unsigned* p) {
    uint32x4 r;
    asm volatile("global_load_dwordx4 %0, %1, off sc0 sc1\n\ts_waitcnt vmcnt(0)"
                 : "=v"(r) : "v"(p) : "memory");
    return r;
}

__device__ __forceinline__ void load_knots(const float* gptr, float* g, float* invA) {
    #pragma unroll
    for (int j = 0; j < KNOTS; ++j) g[j] = gptr[j];
    #pragma unroll
    for (int d = 1; d <= 3; ++d) {
        #pragma unroll
        for (int j = 0; j < 11; ++j) {
            if (j + d <= 11) invA[(d-1)*11 + j] = 1.0f / (g[j+d] - g[j]);
        }
    }
}

// Exact Cox-de Boor (degree 3) + silu — parallel kernels (R2-proven)
__device__ __forceinline__ void basis9(float x, const float* g, const float* invA, float* out) {
    float B[11];
    #pragma unroll
    for (int j = 0; j < 11; ++j)
        B[j] = (x >= g[j] && x < g[j+1]) ? 1.0f : 0.0f;
    #pragma unroll
    for (int d = 1; d <= 3; ++d) {
        #pragma unroll
        for (int j = 0; j < 11; ++j) {
            if (j + d < 11) {
                float left  = (x - g[j]) * invA[(d-1)*11 + j];
                float right = (g[j+d+1] - x) * invA[(d-1)*11 + j + 1];
                B[j] = left * B[j] + right * B[j+1];
            }
        }
    }
    #pragma unroll
    for (int j = 0; j < 8; ++j) out[j] = B[j];
    out[8] = x / (1.0f + expf(-x));
}

// ---------------- build1: xpart weights + packed seq weights + sentinel fill (R10-proven) ----------------
__global__ __launch_bounds__(256) void build1_kernel(
    const float* __restrict__ hu_coef, const float* __restrict__ hu_sb, const float* __restrict__ hu_ssp,
    float* __restrict__ ws)
{
    int idx = blockIdx.x * blockDim.x + threadIdx.x;
    int stride = gridDim.x * blockDim.x;
    // xpart slab: [i<128][k<9][o<512]
    const int N1 = 128 * 9 * 512;
    for (int p = idx; p < N1; p += stride) {
        int o = p & 511; int k = (p >> 9) % 9; int i = p / 4608;
        float v = (k < 8) ? hu_ssp[i*HID + o] * hu_coef[(i*HID + o)*8 + k] : hu_sb[i*HID + o];
        ws[WS_W9HU + p] = v;
    }
    // packed seq slab: [blk<32][th<512][slot<72]
    unsigned* WP = (unsigned*)(ws + WS_WSEQP);
    const int N2 = 32 * 512 * 72;
    for (int p = idx; p < N2; p += stride) {
        int slot = p % 72; int th = (p / 72) & 511; int blk = p / (72 * 512);
        int q = th >> 2, oq = th & 3;
        unsigned pr;
        if (slot < 64) {
            int r = slot >> 4, j = (slot >> 2) & 3, kp = slot & 3;
            int gi = IN_DIM + 4*q + r;
            int o  = blk*16 + oq*4 + j;
            float wlo = hu_ssp[gi*HID + o] * hu_coef[(gi*HID + o)*8 + 2*kp];
            float whi = hu_ssp[gi*HID + o] * hu_coef[(gi*HID + o)*8 + 2*kp + 1];
            pr = bf16rne(wlo) | (bf16rne(whi) << 16);
        } else {
            int e = slot - 64;
            int r = e >> 1, jp = e & 1;
            int gi = IN_DIM + 4*q + r;
            int o0 = blk*16 + oq*4 + 2*jp;
            pr = bf16rne(hu_sb[gi*HID + o0]) | (bf16rne(hu_sb[gi*HID + o0 + 1]) << 16);
        }
        WP[p] = pr;
    }
    // sentinel fill
    unsigned* hc = (unsigned*)(ws + WS_HCOMM);
    for (int p = idx; p < SEQ*HID; p += stride) hc[p] = SENTINEL;
}

// ---------------- build2: output-layer weights (overlays W9HU; runs after seq) ----------------
__global__ __launch_bounds__(256) void build2_kernel(
    const float* __restrict__ out_coef, const float* __restrict__ out_sb, const float* __restrict__ out_ssp,
    float* __restrict__ ws)
{
    int idx = blockIdx.x * blockDim.x + threadIdx.x;
    int stride = gridDim.x * blockDim.x;
    const int N = 512 * 9 * 128;   // [i<512][k<9][o<128]
    for (int p = idx; p < N; p += stride) {
        int o = p & 127; int k = (p >> 7) % 9; int i = p / 1152;
        float v = (k < 8) ? out_ssp[i*OUT_DIM + o] * out_coef[(i*OUT_DIM + o)*8 + k] : out_sb[i*OUT_DIM + o];
        ws[WS_W9HU + p] = v;
    }
}

// ---------------- phase 1: x-part contributions (R2-proven form) ----------------
#define R1 4
__global__ __launch_bounds__(256) void xpart_kernel(
    const float* __restrict__ X, const float* __restrict__ hu_grid, float* __restrict__ ws)
{
    const int tid = threadIdx.x;
    const int t0 = blockIdx.x * R1;
    const float* W9 = ws + WS_W9HU;
    float* xpart = ws + WS_XPART;
    float g[KNOTS], invA[33];
    load_knots(hu_grid, g, invA);

    __shared__ float4 bas4[R1*IN_DIM*3 + (R1*IN_DIM)/16];
    #pragma unroll
    for (int rep = 0; rep < 2; ++rep) {
        int idx = tid + rep*256;
        int r = idx >> 7, i = idx & 127;
        float bv[9];
        basis9(X[(t0 + r)*IN_DIM + i], g, invA, bv);
        int rb = brow(idx);
        bas4[rb]   = make_float4(bv[0], bv[1], bv[2], bv[3]);
        bas4[rb+1] = make_float4(bv[4], bv[5], bv[6], bv[7]);
        bas4[rb+2] = make_float4(bv[8], 0.f, 0.f, 0.f);
    }
    __syncthreads();

    float acc[R1][2];
    #pragma unroll
    for (int r = 0; r < R1; ++r) { acc[r][0] = 0.f; acc[r][1] = 0.f; }

    for (int i = 0; i < IN_DIM; ++i) {
        float w1[9], w2[9];
        #pragma unroll
        for (int k = 0; k < 9; ++k) {
            w1[k] = W9[(i*NK+k)*HID + tid];
            w2[k] = W9[(i*NK+k)*HID + tid + 256];
        }
        #pragma unroll
        for (int r = 0; r < R1; ++r) {
            const float* rp = (const float*)&bas4[brow(r*IN_DIM + i)];
            float4 b0 = ((const float4*)rp)[0], b1 = ((const float4*)rp)[1];
            float b8 = rp[8];
            float s1 = w1[0]*b0.x + w1[1]*b0.y + w1[2]*b0.z + w1[3]*b0.w
                     + w1[4]*b1.x + w1[5]*b1.y + w1[6]*b1.z + w1[7]*b1.w + w1[8]*b8;
            float s2 = w2[0]*b0.x + w2[1]*b0.y + w2[2]*b0.z + w2[3]*b0.w
                     + w2[4]*b1.x + w2[5]*b1.y + w2[6]*b1.z + w2[7]*b1.w + w2[8]*b8;
            acc[r][0] += s1; acc[r][1] += s2;
        }
    }
    #pragma unroll
    for (int r = 0; r < R1; ++r) {
        xpart[(t0+r)*HID + tid]       = acc[r][0];
        xpart[(t0+r)*HID + tid + 256] = acc[r][1];
    }
}

// ---------------- phase 2: sequential recurrence (quad-local basis; 1 barrier; no basis LDS) ----------------
__global__ __launch_bounds__(TPB2, 1) void seq_kernel(
    const float* __restrict__ h0, const float* __restrict__ hu_grid,
    const unsigned* __restrict__ WP,      // packed weights slab
    const float* __restrict__ xpart,
    unsigned* __restrict__ hcomm,         // u32 view of comm slab
    float* __restrict__ hs_out)
{
    const int tid  = threadIdx.x;
    const int blk  = blockIdx.x;
    const int wave = tid >> 6;
    const int lane = tid & 63;
    const int q    = tid >> 2;       // input quad 0..127
    const float g0 = hu_grid[0];
    const float inv_h = 1.0f / (hu_grid[1] - hu_grid[0]);

    // packed register-resident weights (R10-proven layout): 64 spline pairs + 8 silu pairs = 72 u32
    unsigned wsp[4][4][4];   // [r][j][kp]
    unsigned wsl[4][2];      // [r][jp]
    {
        const uint32x4* Wb = (const uint32x4*)(WP + ((size_t)blk*512 + tid)*72);
        #pragma unroll
        for (int r = 0; r < 4; ++r) {
            #pragma unroll
            for (int j = 0; j < 4; ++j) {
                uint32x4 v = Wb[r*4 + j];
                wsp[r][j][0] = v.x; wsp[r][j][1] = v.y; wsp[r][j][2] = v.z; wsp[r][j][3] = v.w;
            }
        }
        uint32x4 s0 = Wb[16], s1 = Wb[17];
        wsl[0][0]=s0.x; wsl[0][1]=s0.y; wsl[1][0]=s0.z; wsl[1][1]=s0.w;
        wsl[2][0]=s1.x; wsl[2][1]=s1.y; wsl[3][0]=s1.z; wsl[3][1]=s1.w;
    }

    __shared__ float red[2][8][4][4];   // [buf][wave][oq][j] — double-buffered: 1 barrier/step

    for (int t = 0; t < SEQ; ++t) {
        const int buf = t & 1;
        float xf = (tid < 16) ? xpart[(size_t)t*HID + blk*16 + tid] : 0.0f;  // poll-independent

        float hv[4];
        if (t == 0) {
            #pragma unroll
            for (int r = 0; r < 4; ++r) hv[r] = h0[4*q + r];
        } else {
            const unsigned* p4 = hcomm + (size_t)(t-1)*HID + 4*q;   // 16B-aligned quad
            int fails = 0;
            for (;;) {
                uint32x4 a = ld4_if(p4);
                if ((a.x != SENTINEL) & (a.y != SENTINEL) & (a.z != SENTINEL) & (a.w != SENTINEL)) {
                    hv[0]=__uint_as_float(a.x); hv[1]=__uint_as_float(a.y);
                    hv[2]=__uint_as_float(a.z); hv[3]=__uint_as_float(a.w);
                    break;
                }
                if (++fails > (1 << 22)) {   // bounded escape; never hit in practice
                    hv[0]=__uint_as_float(a.x); hv[1]=__uint_as_float(a.y);
                    hv[2]=__uint_as_float(a.z); hv[3]=__uint_as_float(a.w);
                    break;
                }
            }
        }

        float p0 = 0.f, p1 = 0.f, p2 = 0.f, p3 = 0.f;
        #pragma unroll
        for (int r = 0; r < 4; ++r) {
            // closed-form uniform cubic basis for this quad-row, fully in registers
            float x  = hv[r];
            float tq = (x - g0) * inv_h;
            float cf = floorf(tq);
            float uu = tq - cf;
            int   c  = (int)cf;
            float um = 1.0f - uu, u2 = uu*uu, u3 = u2*uu;
            float P0 = um*um*um*(1.0f/6.0f);
            float P1 = 0.5f*u3 - u2 + (2.0f/3.0f);
            float P2 = -0.5f*u3 + 0.5f*u2 + 0.5f*uu + (1.0f/6.0f);
            float P3 = u3*(1.0f/6.0f);
            float b[9];
            #pragma unroll
            for (int k = 0; k < 8; ++k) {
                float v = 0.f;
                v = (c == k+3) ? P0 : v;
                v = (c == k+2) ? P1 : v;
                v = (c == k+1) ? P2 : v;
                v = (c == k  ) ? P3 : v;
                b[k] = v;
            }
            b[8] = x * __builtin_amdgcn_rcpf(1.0f + __expf(-x));   // silu

            p0 += blo(wsp[r][0][0])*b[0] + bhi(wsp[r][0][0])*b[1] + blo(wsp[r][0][1])*b[2] + bhi(wsp[r][0][1])*b[3]
                + blo(wsp[r][0][2])*b[4] + bhi(wsp[r][0][2])*b[5] + blo(wsp[r][0][3])*b[6] + bhi(wsp[r][0][3])*b[7]
                + blo(wsl[r][0])*b[8];
            p1 += blo(wsp[r][1][0])*b[0] + bhi(wsp[r][1][0])*b[1] + blo(wsp[r][1][1])*b[2] + bhi(wsp[r][1][1])*b[3]
                + blo(wsp[r][1][2])*b[4] + bhi(wsp[r][1][2])*b[5] + blo(wsp[r][1][3])*b[6] + bhi(wsp[r][1][3])*b[7]
                + bhi(wsl[r][0])*b[8];
            p2 += blo(wsp[r][2][0])*b[0] + bhi(wsp[r][2][0])*b[1] + blo(wsp[r][2][1])*b[2] + bhi(wsp[r][2][1])*b[3]
                + blo(wsp[r][2][2])*b[4] + bhi(wsp[r][2][2])*b[5] + blo(wsp[r][2][3])*b[6] + bhi(wsp[r][2][3])*b[7]
                + blo(wsl[r][1])*b[8];
            p3 += blo(wsp[r][3][0])*b[0] + bhi(wsp[r][3][0])*b[1] + blo(wsp[r][3][1])*b[2] + bhi(wsp[r][3][1])*b[3]
                + blo(wsp[r][3][2])*b[4] + bhi(wsp[r][3][2])*b[5] + blo(wsp[r][3][3])*b[6] + bhi(wsp[r][3][3])*b[7]
                + bhi(wsl[r][1])*b[8];
        }

        // intra-wave reduce over stride-4 lane classes (oq preserved in low 2 bits)
        #pragma unroll
        for (int d = 4; d < 64; d <<= 1) {
            p0 += __shfl_xor(p0, d, 64);
            p1 += __shfl_xor(p1, d, 64);
            p2 += __shfl_xor(p2, d, 64);
            p3 += __shfl_xor(p3, d, 64);
        }
        if (lane < 4) {
            red[buf][wave][lane][0] = p0;
            red[buf][wave][lane][1] = p1;
            red[buf][wave][lane][2] = p2;
            red[buf][wave][lane][3] = p3;
        }
        __syncthreads();   // the ONLY barrier per step (red is double-buffered)
        if (tid < 16) {
            float s = xf;
            #pragma unroll
            for (int wv = 0; wv < 8; ++wv) s += red[buf][wv][tid>>2][tid&3];
            __hip_atomic_store(&hcomm[(size_t)t*HID + blk*16 + tid], __float_as_uint(s),
                               __ATOMIC_RELAXED, __HIP_MEMORY_SCOPE_AGENT);
            hs_out[(size_t)t*HID + blk*16 + tid] = s;
        }
    }
}

// ---------------- phase 3: output layer (R2-proven form) ----------------
#define R3 2
__global__ __launch_bounds__(256) void outlayer_kernel(
    const float* __restrict__ out_grid, float* __restrict__ ws, float* __restrict__ d_out)
{
    const int tid = threadIdx.x;
    const int t0 = blockIdx.x * R3;
    const float* W9o = ws + WS_W9HU;   // overlaid by build2
    const float* hs = d_out + (size_t)SEQ*OUT_DIM;
    float g[KNOTS], invA[33];
    load_knots(out_grid, g, invA);

    __shared__ float4 bas4[R3*HID*3 + (R3*HID)/16];
    #pragma unroll
    for (int rep = 0; rep < 4; ++rep) {
        int idx = tid + rep*256;
        int r = idx >> 9, i = idx & 511;
        float bv[9];
        basis9(hs[(size_t)(t0+r)*HID + i], g, invA, bv);
        int rb = brow(idx);
        bas4[rb]   = make_float4(bv[0], bv[1], bv[2], bv[3]);
        bas4[rb+1] = make_float4(bv[4], bv[5], bv[6], bv[7]);
        bas4[rb+2] = make_float4(bv[8], 0.f, 0.f, 0.f);
    }
    __syncthreads();

    const int oo = tid & 127;
    const int half = tid >> 7;
    float acc[R3] = {0.f, 0.f};
    for (int ii = 0; ii < 256; ++ii) {
        int i = half*256 + ii;
        float wv[9];
        #pragma unroll
        for (int k = 0; k < 9; ++k) wv[k] = W9o[(i*NK+k)*OUT_DIM + oo];
        #pragma unroll
        for (int r = 0; r < R3; ++r) {
            const float* rp = (const float*)&bas4[brow(r*HID + i)];
            float4 b0 = ((const float4*)rp)[0], b1 = ((const float4*)rp)[1];
            float b8 = rp[8];
            acc[r] += wv[0]*b0.x + wv[1]*b0.y + wv[2]*b0.z + wv[3]*b0.w
                    + wv[4]*b1.x + wv[5]*b1.y + wv[6]*b1.z + wv[7]*b1.w + wv[8]*b8;
        }
    }
    __shared__ float red[2][R3][128];
    red[half][0][oo] = acc[0];
    red[half][1][oo] = acc[1];
    __syncthreads();
    {
        int rr = tid >> 7, o2 = tid & 127;
        d_out[(size_t)(t0+rr)*OUT_DIM + o2] = red[0][rr][o2] + red[1][rr][o2];
    }
}

extern "C" void kernel_launch(void* const* d_in, const int* in_sizes, int n_in,
                              void* d_out, int out_size, void* d_ws, size_t ws_size,
                              hipStream_t stream) {
    (void)in_sizes; (void)n_in; (void)out_size; (void)ws_size;
    const float* X        = (const float*)d_in[0];
    const float* h0       = (const float*)d_in[1];
    const float* hu_grid  = (const float*)d_in[2];
    const float* hu_coef  = (const float*)d_in[3];
    const float* hu_sb    = (const float*)d_in[4];
    const float* hu_ssp   = (const float*)d_in[5];
    const float* out_grid = (const float*)d_in[6];
    const float* out_coef = (const float*)d_in[7];
    const float* out_sb   = (const float*)d_in[8];
    const float* out_ssp  = (const float*)d_in[9];
    float* out = (float*)d_out;
    float* ws  = (float*)d_ws;

    hipLaunchKernelGGL(build1_kernel, dim3(2048), dim3(256), 0, stream,
                       hu_coef, hu_sb, hu_ssp, ws);
    hipLaunchKernelGGL(xpart_kernel, dim3(SEQ/R1), dim3(256), 0, stream, X, hu_grid, ws);
    hipLaunchKernelGGL(seq_kernel, dim3(NWG), dim3(TPB2), 0, stream,
                       h0, hu_grid,
                       (const unsigned*)(ws + WS_WSEQP),
                       ws + WS_XPART,
                       (unsigned*)(ws + WS_HCOMM),
                       out + (size_t)SEQ*OUT_DIM);
    hipLaunchKernelGGL(build2_kernel, dim3(1024), dim3(256), 0, stream,
                       out_coef, out_sb, out_ssp, ws);
    hipLaunchKernelGGL(outlayer_kernel, dim3(SEQ/R3), dim3(256), 0, stream, out_grid, ws, out);
}

// Round 14
// 16751.868 us; speedup vs baseline: 2.6491x; 1.2200x over previous
//
#include <hip/hip_runtime.h>
#include <math.h>

#define SEQ 8192
#define IN_DIM 128
#define HID 512
#define OUT_DIM 128
#define NK 9      // 8 spline basis + 1 silu slot
#define KNOTS 12

// ws layout (floats). W9HU region reused for W9O by build2 (after seq).
#define WS_W9HU  0                           // 128*9*512 = 589,824 (xpart W); later W9O (512*9*128)
#define WS_WSEQP 589824                      // 32*512*72 packed bf16-pair weights (as u32)
#define WS_XPART (WS_WSEQP + 1179648)        // 8192*512
#define WS_HCOMM (WS_XPART + 4194304)        // 8192*512
#define WS_TOTAL (WS_HCOMM + 4194304)        // 10,158,080 floats = 40.6 MB

#define SENTINEL 0x7FA0DEADu   // sNaN payload; never produced by arithmetic

#define NWG 32
#define TPB2 512

__device__ __forceinline__ int brow(int ib) { return ib*3 + (ib >> 4); }  // R2-proven (stride-16 reads)
// seq LDS dword-offset: injective, monotone; stride-4-row reads cover all 8 bank-quads (2-way max)
__device__ __forceinline__ int boff(int row) { return row*12 + ((row >> 2) << 2); }

__device__ __forceinline__ unsigned bf16rne(float f) {
    unsigned b = __float_as_uint(f);
    return (b + 0x7fffu + ((b >> 16) & 1u)) >> 16;
}
__device__ __forceinline__ float blo(unsigned p) { return __uint_as_float(p << 16); }
__device__ __forceinline__ float bhi(unsigned p) { return __uint_as_float(p & 0xffff0000u); }

__device__ __forceinline__ void load_knots(const float* gptr, float* g, float* invA) {
    #pragma unroll
    for (int j = 0; j < KNOTS; ++j) g[j] = gptr[j];
    #pragma unroll
    for (int d = 1; d <= 3; ++d) {
        #pragma unroll
        for (int j = 0; j < 11; ++j) {
            if (j + d <= 11) invA[(d-1)*11 + j] = 1.0f / (g[j+d] - g[j]);
        }
    }
}

// Exact Cox-de Boor (degree 3) + silu — parallel kernels (R2-proven)
__device__ __forceinline__ void basis9(float x, const float* g, const float* invA, float* out) {
    float B[11];
    #pragma unroll
    for (int j = 0; j < 11; ++j)
        B[j] = (x >= g[j] && x < g[j+1]) ? 1.0f : 0.0f;
    #pragma unroll
    for (int d = 1; d <= 3; ++d) {
        #pragma unroll
        for (int j = 0; j < 11; ++j) {
            if (j + d < 11) {
                float left  = (x - g[j]) * invA[(d-1)*11 + j];
                float right = (g[j+d+1] - x) * invA[(d-1)*11 + j + 1];
                B[j] = left * B[j] + right * B[j+1];
            }
        }
    }
    #pragma unroll
    for (int j = 0; j < 8; ++j) out[j] = B[j];
    out[8] = x / (1.0f + expf(-x));
}

// ---------------- build1: xpart weights + packed seq weights + sentinel fill ----------------
__global__ __launch_bounds__(256) void build1_kernel(
    const float* __restrict__ hu_coef, const float* __restrict__ hu_sb, const float* __restrict__ hu_ssp,
    float* __restrict__ ws)
{
    int idx = blockIdx.x * blockDim.x + threadIdx.x;
    int stride = gridDim.x * blockDim.x;
    // xpart slab: [i<128][k<9][o<512]
    const int N1 = 128 * 9 * 512;
    for (int p = idx; p < N1; p += stride) {
        int o = p & 511; int k = (p >> 9) % 9; int i = p / 4608;
        float v = (k < 8) ? hu_ssp[i*HID + o] * hu_coef[(i*HID + o)*8 + k] : hu_sb[i*HID + o];
        ws[WS_W9HU + p] = v;
    }
    // packed seq slab: [blk<32][th<512][slot<72]
    unsigned* WP = (unsigned*)(ws + WS_WSEQP);
    const int N2 = 32 * 512 * 72;
    for (int p = idx; p < N2; p += stride) {
        int slot = p % 72; int th = (p / 72) & 511; int blk = p / (72 * 512);
        int q = th >> 2, oq = th & 3;
        unsigned pr;
        if (slot < 64) {
            int r = slot >> 4, j = (slot >> 2) & 3, kp = slot & 3;
            int gi = IN_DIM + 4*q + r;
            int o  = blk*16 + oq*4 + j;
            float wlo = hu_ssp[gi*HID + o] * hu_coef[(gi*HID + o)*8 + 2*kp];
            float whi = hu_ssp[gi*HID + o] * hu_coef[(gi*HID + o)*8 + 2*kp + 1];
            pr = bf16rne(wlo) | (bf16rne(whi) << 16);
        } else {
            int e = slot - 64;
            int r = e >> 1, jp = e & 1;
            int gi = IN_DIM + 4*q + r;
            int o0 = blk*16 + oq*4 + 2*jp;
            pr = bf16rne(hu_sb[gi*HID + o0]) | (bf16rne(hu_sb[gi*HID + o0 + 1]) << 16);
        }
        WP[p] = pr;
    }
    // sentinel fill
    unsigned* hc = (unsigned*)(ws + WS_HCOMM);
    for (int p = idx; p < SEQ*HID; p += stride) hc[p] = SENTINEL;
}

// ---------------- build2: output-layer weights (overlays W9HU region; runs after seq) ----------------
__global__ __launch_bounds__(256) void build2_kernel(
    const float* __restrict__ out_coef, const float* __restrict__ out_sb, const float* __restrict__ out_ssp,
    float* __restrict__ ws)
{
    int idx = blockIdx.x * blockDim.x + threadIdx.x;
    int stride = gridDim.x * blockDim.x;
    const int N = 512 * 9 * 128;   // [i<512][k<9][o<128]
    for (int p = idx; p < N; p += stride) {
        int o = p & 127; int k = (p >> 7) % 9; int i = p / 1152;
        float v = (k < 8) ? out_ssp[i*OUT_DIM + o] * out_coef[(i*OUT_DIM + o)*8 + k] : out_sb[i*OUT_DIM + o];
        ws[WS_W9HU + p] = v;
    }
}

// ---------------- phase 1: x-part contributions (R2-proven form) ----------------
#define R1 4
__global__ __launch_bounds__(256) void xpart_kernel(
    const float* __restrict__ X, const float* __restrict__ hu_grid, float* __restrict__ ws)
{
    const int tid = threadIdx.x;
    const int t0 = blockIdx.x * R1;
    const float* W9 = ws + WS_W9HU;
    float* xpart = ws + WS_XPART;
    float g[KNOTS], invA[33];
    load_knots(hu_grid, g, invA);

    __shared__ float4 bas4[R1*IN_DIM*3 + (R1*IN_DIM)/16];
    #pragma unroll
    for (int rep = 0; rep < 2; ++rep) {
        int idx = tid + rep*256;
        int r = idx >> 7, i = idx & 127;
        float bv[9];
        basis9(X[(t0 + r)*IN_DIM + i], g, invA, bv);
        int rb = brow(idx);
        bas4[rb]   = make_float4(bv[0], bv[1], bv[2], bv[3]);
        bas4[rb+1] = make_float4(bv[4], bv[5], bv[6], bv[7]);
        bas4[rb+2] = make_float4(bv[8], 0.f, 0.f, 0.f);
    }
    __syncthreads();

    float acc[R1][2];
    #pragma unroll
    for (int r = 0; r < R1; ++r) { acc[r][0] = 0.f; acc[r][1] = 0.f; }

    for (int i = 0; i < IN_DIM; ++i) {
        float w1[9], w2[9];
        #pragma unroll
        for (int k = 0; k < 9; ++k) {
            w1[k] = W9[(i*NK+k)*HID + tid];
            w2[k] = W9[(i*NK+k)*HID + tid + 256];
        }
        #pragma unroll
        for (int r = 0; r < R1; ++r) {
            const float* rp = (const float*)&bas4[brow(r*IN_DIM + i)];
            float4 b0 = ((const float4*)rp)[0], b1 = ((const float4*)rp)[1];
            float b8 = rp[8];
            float s1 = w1[0]*b0.x + w1[1]*b0.y + w1[2]*b0.z + w1[3]*b0.w
                     + w1[4]*b1.x + w1[5]*b1.y + w1[6]*b1.z + w1[7]*b1.w + w1[8]*b8;
            float s2 = w2[0]*b0.x + w2[1]*b0.y + w2[2]*b0.z + w2[3]*b0.w
                     + w2[4]*b1.x + w2[5]*b1.y + w2[6]*b1.z + w2[7]*b1.w + w2[8]*b8;
            acc[r][0] += s1; acc[r][1] += s2;
        }
    }
    #pragma unroll
    for (int r = 0; r < R1; ++r) {
        xpart[(t0+r)*HID + tid]       = acc[r][0];
        xpart[(t0+r)*HID + tid + 256] = acc[r][1];
    }
}

// ---------------- phase 2: sequential recurrence (R6 skeleton; bf16-packed reg weights) ----------------
__global__ __launch_bounds__(TPB2, 1) void seq_kernel(
    const float* __restrict__ h0, const float* __restrict__ hu_grid,
    const unsigned* __restrict__ WP,      // packed weights slab
    const float* __restrict__ xpart,
    unsigned* __restrict__ hcomm,         // u32 view of comm slab
    float* __restrict__ hs_out)
{
    const int tid  = threadIdx.x;
    const int blk  = blockIdx.x;
    const int lane = tid & 63;
    const int wave = tid >> 6;
    const int oq   = tid & 3;        // output quad (4-way broadcast rows)
    const int q    = tid >> 2;       // input quad 0..127
    const float g0 = hu_grid[0];
    const float inv_h = 1.0f / (hu_grid[1] - hu_grid[0]);

    // packed register-resident weights: 64 spline pairs + 8 silu pairs = 72 u32
    unsigned wsp[4][4][4];   // [r][j][kp]
    unsigned wsl[4][2];      // [r][jp]
    {
        const uint4* Wb = (const uint4*)(WP + ((size_t)blk*512 + tid)*72);
        #pragma unroll
        for (int r = 0; r < 4; ++r) {
            #pragma unroll
            for (int j = 0; j < 4; ++j) {
                uint4 v = Wb[r*4 + j];
                wsp[r][j][0] = v.x; wsp[r][j][1] = v.y; wsp[r][j][2] = v.z; wsp[r][j][3] = v.w;
            }
        }
        uint4 s0 = Wb[16];      // slots 64..67
        uint4 s1 = Wb[17];      // slots 68..71
        wsl[0][0]=s0.x; wsl[0][1]=s0.y; wsl[1][0]=s0.z; wsl[1][1]=s0.w;
        wsl[2][0]=s1.x; wsl[2][1]=s1.y; wsl[3][0]=s1.z; wsl[3][1]=s1.w;
    }

    __shared__ float basf[6656];
    __shared__ float red[8][4][4];

    for (int t = 0; t < SEQ; ++t) {
        float xf = (tid < 16) ? xpart[(size_t)t*HID + blk*16 + tid] : 0.0f;  // poll-independent prefetch

        float hv;
        if (t == 0) {
            hv = h0[tid];
        } else {
            const unsigned* pp = &hcomm[(size_t)(t-1)*HID + tid];
            unsigned u = __hip_atomic_load(pp, __ATOMIC_RELAXED, __HIP_MEMORY_SCOPE_AGENT);
            int sp = 0;
            while (u == SENTINEL && ++sp < (1 << 24))
                u = __hip_atomic_load(pp, __ATOMIC_RELAXED, __HIP_MEMORY_SCOPE_AGENT);
            hv = __uint_as_float(u);
        }

        // closed-form uniform cubic basis -> LDS row boff(tid)
        {
            float* rowp = basf + boff(tid);
            float tq = (hv - g0) * inv_h;
            float cf = floorf(tq);
            float u  = tq - cf;
            int   c  = (int)cf;
            float si = hv * __builtin_amdgcn_rcpf(1.0f + __expf(-hv));
            ((float4*)rowp)[0] = make_float4(0.f, 0.f, 0.f, 0.f);
            ((float4*)rowp)[1] = make_float4(0.f, 0.f, 0.f, 0.f);
            rowp[8] = si;
            if (c >= 0 && c <= 10) {
                float um = 1.0f - u, u2 = u*u, u3 = u2*u;
                float P0 = um*um*um*(1.0f/6.0f);
                float P1 = 0.5f*u3 - u2 + (2.0f/3.0f);
                float P2 = -0.5f*u3 + 0.5f*u2 + 0.5f*u + (1.0f/6.0f);
                float P3 = u3*(1.0f/6.0f);
                int j0 = c - 3;
                if (j0     >= 0)              rowp[j0]     = P0;
                if (j0 + 1 >= 0 && j0+1 <= 7) rowp[j0 + 1] = P1;
                if (j0 + 2 >= 0 && j0+2 <= 7) rowp[j0 + 2] = P2;
                if (j0 + 3 <= 7)              rowp[j0 + 3] = P3;
            }
        }
        __syncthreads();

        float p0 = 0.f, p1 = 0.f, p2 = 0.f, p3 = 0.f;
        #pragma unroll
        for (int r = 0; r < 4; ++r) {
            const float* rp = basf + boff(4*q + r);
            float4 b0 = ((const float4*)rp)[0], b1 = ((const float4*)rp)[1];
            float b8 = rp[8];
            p0 += blo(wsp[r][0][0])*b0.x + bhi(wsp[r][0][0])*b0.y + blo(wsp[r][0][1])*b0.z + bhi(wsp[r][0][1])*b0.w
                + blo(wsp[r][0][2])*b1.x + bhi(wsp[r][0][2])*b1.y + blo(wsp[r][0][3])*b1.z + bhi(wsp[r][0][3])*b1.w
                + blo(wsl[r][0])*b8;
            p1 += blo(wsp[r][1][0])*b0.x + bhi(wsp[r][1][0])*b0.y + blo(wsp[r][1][1])*b0.z + bhi(wsp[r][1][1])*b0.w
                + blo(wsp[r][1][2])*b1.x + bhi(wsp[r][1][2])*b1.y + blo(wsp[r][1][3])*b1.z + bhi(wsp[r][1][3])*b1.w
                + bhi(wsl[r][0])*b8;
            p2 += blo(wsp[r][2][0])*b0.x + bhi(wsp[r][2][0])*b0.y + blo(wsp[r][2][1])*b0.z + bhi(wsp[r][2][1])*b0.w
                + blo(wsp[r][2][2])*b1.x + bhi(wsp[r][2][2])*b1.y + blo(wsp[r][2][3])*b1.z + bhi(wsp[r][2][3])*b1.w
                + blo(wsl[r][1])*b8;
            p3 += blo(wsp[r][3][0])*b0.x + bhi(wsp[r][3][0])*b0.y + blo(wsp[r][3][1])*b0.z + bhi(wsp[r][3][1])*b0.w
                + blo(wsp[r][3][2])*b1.x + bhi(wsp[r][3][2])*b1.y + blo(wsp[r][3][3])*b1.z + bhi(wsp[r][3][3])*b1.w
                + bhi(wsl[r][1])*b8;
        }
        #pragma unroll
        for (int d = 4; d < 64; d <<= 1) {
            p0 += __shfl_xor(p0, d, 64);
            p1 += __shfl_xor(p1, d, 64);
            p2 += __shfl_xor(p2, d, 64);
            p3 += __shfl_xor(p3, d, 64);
        }
        if (lane < 4) {
            red[wave][lane][0] = p0;
            red[wave][lane][1] = p1;
            red[wave][lane][2] = p2;
            red[wave][lane][3] = p3;
        }
        __syncthreads();
        if (tid < 16) {
            float s = xf;
            #pragma unroll
            for (int wv = 0; wv < 8; ++wv) s += red[wv][tid>>2][tid&3];
            __hip_atomic_store(&hcomm[(size_t)t*HID + blk*16 + tid], __float_as_uint(s),
                               __ATOMIC_RELAXED, __HIP_MEMORY_SCOPE_AGENT);
            hs_out[(size_t)t*HID + blk*16 + tid] = s;
        }
        __syncthreads();   // WAR: basf/red rewritten next step
    }
}

// ---------------- phase 3: output layer (R2-proven form) ----------------
#define R3 2
__global__ __launch_bounds__(256) void outlayer_kernel(
    const float* __restrict__ out_grid, float* __restrict__ ws, float* __restrict__ d_out)
{
    const int tid = threadIdx.x;
    const int t0 = blockIdx.x * R3;
    const float* W9o = ws + WS_W9HU;   // overlaid by build2
    const float* hs = d_out + (size_t)SEQ*OUT_DIM;
    float g[KNOTS], invA[33];
    load_knots(out_grid, g, invA);

    __shared__ float4 bas4[R3*HID*3 + (R3*HID)/16];
    #pragma unroll
    for (int rep = 0; rep < 4; ++rep) {
        int idx = tid + rep*256;
        int r = idx >> 9, i = idx & 511;
        float bv[9];
        basis9(hs[(size_t)(t0+r)*HID + i], g, invA, bv);
        int rb = brow(idx);
        bas4[rb]   = make_float4(bv[0], bv[1], bv[2], bv[3]);
        bas4[rb+1] = make_float4(bv[4], bv[5], bv[6], bv[7]);
        bas4[rb+2] = make_float4(bv[8], 0.f, 0.f, 0.f);
    }
    __syncthreads();

    const int oo = tid & 127;
    const int half = tid >> 7;
    float acc[R3] = {0.f, 0.f};
    for (int ii = 0; ii < 256; ++ii) {
        int i = half*256 + ii;
        float wv[9];
        #pragma unroll
        for (int k = 0; k < 9; ++k) wv[k] = W9o[(i*NK+k)*OUT_DIM + oo];
        #pragma unroll
        for (int r = 0; r < R3; ++r) {
            const float* rp = (const float*)&bas4[brow(r*HID + i)];
            float4 b0 = ((const float4*)rp)[0], b1 = ((const float4*)rp)[1];
            float b8 = rp[8];
            acc[r] += wv[0]*b0.x + wv[1]*b0.y + wv[2]*b0.z + wv[3]*b0.w
                    + wv[4]*b1.x + wv[5]*b1.y + wv[6]*b1.z + wv[7]*b1.w + wv[8]*b8;
        }
    }
    __shared__ float red[2][R3][128];
    red[half][0][oo] = acc[0];
    red[half][1][oo] = acc[1];
    __syncthreads();
    {
        int rr = tid >> 7, o2 = tid & 127;
        d_out[(size_t)(t0+rr)*OUT_DIM + o2] = red[0][rr][o2] + red[1][rr][o2];
    }
}

extern "C" void kernel_launch(void* const* d_in, const int* in_sizes, int n_in,
                              void* d_out, int out_size, void* d_ws, size_t ws_size,
                              hipStream_t stream) {
    (void)in_sizes; (void)n_in; (void)out_size; (void)ws_size;
    const float* X        = (const float*)d_in[0];
    const float* h0       = (const float*)d_in[1];
    const float* hu_grid  = (const float*)d_in[2];
    const float* hu_coef  = (const float*)d_in[3];
    const float* hu_sb    = (const float*)d_in[4];
    const float* hu_ssp   = (const float*)d_in[5];
    const float* out_grid = (const float*)d_in[6];
    const float* out_coef = (const float*)d_in[7];
    const float* out_sb   = (const float*)d_in[8];
    const float* out_ssp  = (const float*)d_in[9];
    float* out = (float*)d_out;
    float* ws  = (float*)d_ws;

    hipLaunchKernelGGL(build1_kernel, dim3(2048), dim3(256), 0, stream,
                       hu_coef, hu_sb, hu_ssp, ws);
    hipLaunchKernelGGL(xpart_kernel, dim3(SEQ/R1), dim3(256), 0, stream, X, hu_grid, ws);
    hipLaunchKernelGGL(seq_kernel, dim3(NWG), dim3(TPB2), 0, stream,
                       h0, hu_grid,
                       (const unsigned*)(ws + WS_WSEQP),
                       ws + WS_XPART,
                       (unsigned*)(ws + WS_HCOMM),
                       out + (size_t)SEQ*OUT_DIM);
    hipLaunchKernelGGL(build2_kernel, dim3(1024), dim3(256), 0, stream,
                       out_coef, out_sb, out_ssp, ws);
    hipLaunchKernelGGL(outlayer_kernel, dim3(SEQ/R3), dim3(256), 0, stream, out_grid, ws, out);
}